// Round 4
// baseline (105.770 us; speedup 1.0000x reference)
//
#include <hip/hip_runtime.h>
#include <hip/hip_cooperative_groups.h>
#include <math.h>
#include <stdint.h>

#define N 2048
#define D 128
#define JS 16            // j-slices
#define BM 128           // i-rows per block
#define BN 128           // j-cols per block (slice width)
#define NB 256           // blocks = (N/BM) * JS = 16*16
#define NT 512           // threads = 8 waves

namespace cg = cooperative_groups;

typedef __attribute__((ext_vector_type(8))) short bf16x8;
typedef __attribute__((ext_vector_type(4))) float f32x4;

// round-to-nearest-even fp32 -> bf16, also returns the bf16 value as fp32
__device__ __forceinline__ ushort f2bf_rne(float x, float* back) {
    uint32_t u = __float_as_uint(x);
    uint32_t r = u + 0x7FFFu + ((u >> 16) & 1u);
    ushort h = (ushort)(r >> 16);
    *back = __uint_as_float(((uint32_t)h) << 16);
    return h;
}

__global__ __launch_bounds__(NT, 2) void fused_kernel(
    const float* __restrict__ q, const int* __restrict__ tgt,
    ushort* __restrict__ H, ushort* __restrict__ L, float* __restrict__ norms,
    float* __restrict__ wpv, int* __restrict__ wpi,
    float* __restrict__ wnv, int* __restrict__ wni,
    float* __restrict__ bpart, float* __restrict__ out) {
    __shared__ ushort HJ[BN * D];  // 32 KB, XOR-swizzled rows (256 B/row)
    __shared__ ushort LJ[BN * D];  // 32 KB
    cg::grid_group grid = cg::this_grid();

    const int b = blockIdx.x;
    const int tid = threadIdx.x;
    const int w = tid >> 6;
    const int lane = tid & 63;

    // ================= Phase A: bf16 split + exact norms (1 row / wave) ======
    {
        const int r = b * 8 + w;
        float2 v = reinterpret_cast<const float2*>(q)[r * (D / 2) + lane];
        float hbx, hby, d_;
        ushort hx = f2bf_rne(v.x, &hbx);
        ushort lx = f2bf_rne(v.x - hbx, &d_);
        ushort hy = f2bf_rne(v.y, &hby);
        ushort ly = f2bf_rne(v.y - hby, &d_);
        reinterpret_cast<uint*>(H)[r * (D / 2) + lane] = (uint)hx | ((uint)hy << 16);
        reinterpret_cast<uint*>(L)[r * (D / 2) + lane] = (uint)lx | ((uint)ly << 16);
        float ns = fmaf(v.x, v.x, v.y * v.y);
#pragma unroll
        for (int m = 1; m <= 32; m <<= 1) ns += __shfl_xor(ns, m);
        if (lane == 0) norms[r] = ns;
    }
    grid.sync();

    // ================= Phase B: MFMA pair scan ===============================
    {
        const int ib = b >> 4;
        const int s = b & 15;
        const int i0 = ib * BM;
        const int j0 = s * BN;
        const int lr = lane & 15;  // fragment row / C col
        const int h = lane >> 4;   // 0..3

        // stage j-slice into LDS, swizzled: byte ^= (row&7)<<4 (16B granules)
        for (int c = tid; c < BN * 16; c += NT) {
            int row = c >> 4, col = c & 15;
            int boff = row * 256 + ((col * 16) ^ ((row & 7) << 4));
            uint4 vh = reinterpret_cast<const uint4*>(H)[(j0 + row) * (D / 8) + col];
            *reinterpret_cast<uint4*>((char*)HJ + boff) = vh;
            uint4 vl = reinterpret_cast<const uint4*>(L)[(j0 + row) * (D / 8) + col];
            *reinterpret_cast<uint4*>((char*)LJ + boff) = vl;
        }

        // A fragments (1 row-tile of 16 per wave), held in registers
        const int rowbase = i0 + w * 16;
        bf16x8 AH[4], AL[4];
#pragma unroll
        for (int kk = 0; kk < 4; ++kk) {
            int r = rowbase + lr;
            AH[kk] = *reinterpret_cast<const bf16x8*>(&H[r * D + kk * 32 + h * 8]);
            AL[kk] = *reinterpret_cast<const bf16x8*>(&L[r * D + kk * 32 + h * 8]);
        }
        float ni[4]; int ti[4];
#pragma unroll
        for (int m = 0; m < 4; ++m) {
            int r = rowbase + h * 4 + m;
            ni[m] = norms[r];
            ti[m] = tgt[r];
        }
        float njr[8]; int tjr[8];
#pragma unroll
        for (int ct = 0; ct < 8; ++ct) {
            int jg = j0 + ct * 16 + lr;
            njr[ct] = norms[jg];
            tjr[ct] = tgt[jg];
        }

        float bpv[4], bnv[4];
        int bpi[4], bni[4];
#pragma unroll
        for (int m = 0; m < 4; ++m) {
            bpv[m] = -INFINITY; bpi[m] = 0;
            bnv[m] = INFINITY;  bni[m] = 0;
        }

        __syncthreads();

        for (int ct = 0; ct < BN / 16; ++ct) {
            const int brow = ct * 16 + lr;
            const int bswz = (brow & 7) << 4;
            const char* hbase = (const char*)HJ + brow * 256;
            const char* lbase = (const char*)LJ + brow * 256;
            bf16x8 BH[4], BL[4];
#pragma unroll
            for (int kk = 0; kk < 4; ++kk) {
                int off = (kk * 64 + h * 16) ^ bswz;
                BH[kk] = *reinterpret_cast<const bf16x8*>(hbase + off);
                BL[kk] = *reinterpret_cast<const bf16x8*>(lbase + off);
            }
            f32x4 acc = (f32x4){0.f, 0.f, 0.f, 0.f};
#pragma unroll
            for (int kk = 0; kk < 4; ++kk)
                acc = __builtin_amdgcn_mfma_f32_16x16x32_bf16(AH[kk], BH[kk], acc, 0, 0, 0);
#pragma unroll
            for (int kk = 0; kk < 4; ++kk)
                acc = __builtin_amdgcn_mfma_f32_16x16x32_bf16(AH[kk], BL[kk], acc, 0, 0, 0);
#pragma unroll
            for (int kk = 0; kk < 4; ++kk)
                acc = __builtin_amdgcn_mfma_f32_16x16x32_bf16(AL[kk], BH[kk], acc, 0, 0, 0);
#pragma unroll
            for (int kk = 0; kk < 4; ++kk)
                acc = __builtin_amdgcn_mfma_f32_16x16x32_bf16(AL[kk], BL[kk], acc, 0, 0, 0);

            const int jg = j0 + ct * 16 + lr;
#pragma unroll
            for (int m = 0; m < 4; ++m) {
                const int ig = rowbase + h * 4 + m;
                const float dist = fmaf(-2.f, acc[m], ni[m] + njr[ct]);
                const bool same = (ti[m] == tjr[ct]);
                const bool diag = (ig == jg);
                const float pmv = diag ? -INFINITY : (same ? dist : 0.f);
                if (pmv > bpv[m]) { bpv[m] = pmv; bpi[m] = jg; }
                const float nmv = (same || diag) ? INFINITY : dist;
                if (nmv < bnv[m]) { bnv[m] = nmv; bni[m] = jg; }
            }
        }

        // merge across the 16 lanes sharing each C row (index tie-break)
#pragma unroll
        for (int mask = 1; mask <= 8; mask <<= 1) {
#pragma unroll
            for (int m = 0; m < 4; ++m) {
                float ov = __shfl_xor(bpv[m], mask);
                int oi = __shfl_xor(bpi[m], mask);
                if (ov > bpv[m] || (ov == bpv[m] && oi < bpi[m])) {
                    bpv[m] = ov; bpi[m] = oi;
                }
                float onv = __shfl_xor(bnv[m], mask);
                int oni = __shfl_xor(bni[m], mask);
                if (onv < bnv[m] || (onv == bnv[m] && oni < bni[m])) {
                    bnv[m] = onv; bni[m] = oni;
                }
            }
        }
        if (lr == 0) {
#pragma unroll
            for (int m = 0; m < 4; ++m) {
                int r = rowbase + h * 4 + m;
                int idx = r * JS + s;
                wpv[idx] = bpv[m]; wpi[idx] = bpi[m];
                wnv[idx] = bnv[m]; wni[idx] = bni[m];
            }
        }
    }
    grid.sync();

    // ================= Phase C: slice merge + exact recompute (1 row / wave) =
    {
        float* sred = (float*)HJ;  // LDS reuse (phase B done grid-wide)
        const int i = b * 8 + w;
        const int l = lane & 15;
        float pv = wpv[i * JS + l];
        int pi = wpi[i * JS + l];
        float nv = wnv[i * JS + l];
        int ng = wni[i * JS + l];
#pragma unroll
        for (int mask = 1; mask <= 8; mask <<= 1) {
            float opv = __shfl_xor(pv, mask);
            int opi = __shfl_xor(pi, mask);
            if (opv > pv || (opv == pv && opi < pi)) { pv = opv; pi = opi; }
            float onv = __shfl_xor(nv, mask);
            int oni = __shfl_xor(ng, mask);
            if (onv < nv || (onv == nv && oni < ng)) { nv = onv; ng = oni; }
        }
        const float2* q2 = reinterpret_cast<const float2*>(q);
        float2 a = q2[i * (D / 2) + lane];
        float2 p = q2[pi * (D / 2) + lane];
        float2 g = q2[ng * (D / 2) + lane];
        float dp = (a.x - p.x) * (a.x - p.x) + (a.y - p.y) * (a.y - p.y);
        float dn = (a.x - g.x) * (a.x - g.x) + (a.y - g.y) * (a.y - g.y);
#pragma unroll
        for (int mask = 1; mask <= 32; mask <<= 1) {
            dp += __shfl_xor(dp, mask);
            dn += __shfl_xor(dn, mask);
        }
        if (lane == 0) sred[w] = fmaxf(0.f, 1.0f - dp + dn);
        __syncthreads();
        if (tid == 0) {
            float t = 0.f;
#pragma unroll
            for (int k = 0; k < 8; ++k) t += sred[k];
            bpart[b] = t;
        }
    }
    grid.sync();

    // ================= Phase D: final deterministic tree-sum (block 0) =======
    if (b == 0) {
        float* sred = (float*)HJ;
        sred[tid] = (tid < NB) ? bpart[tid] : 0.f;
        __syncthreads();
        for (int s2 = NT / 2; s2 > 0; s2 >>= 1) {
            if (tid < s2) sred[tid] += sred[tid + s2];
            __syncthreads();
        }
        if (tid == 0) out[0] = sred[0] / (float)N;
    }
}

extern "C" void kernel_launch(void* const* d_in, const int* in_sizes, int n_in,
                              void* d_out, int out_size, void* d_ws, size_t ws_size,
                              hipStream_t stream) {
    const float* q = (const float*)d_in[0];
    const int* tgt = (const int*)d_in[1];

    ushort* H = (ushort*)d_ws;              // N*D bf16
    ushort* L = H + N * D;                  // N*D bf16
    float* norms = (float*)(L + N * D);     // N
    float* wpv = norms + N;                 // N*JS
    int* wpi = (int*)(wpv + N * JS);        // N*JS
    float* wnv = (float*)(wpi + N * JS);    // N*JS
    int* wni = (int*)(wnv + N * JS);        // N*JS
    float* bpart = (float*)(wni + N * JS);  // NB
    float* out = (float*)d_out;

    void* args[] = {(void*)&q, (void*)&tgt, (void*)&H, (void*)&L, (void*)&norms,
                    (void*)&wpv, (void*)&wpi, (void*)&wnv, (void*)&wni,
                    (void*)&bpart, (void*)&out};
    hipLaunchCooperativeKernel((const void*)fused_kernel, dim3(NB), dim3(NT),
                               args, 0, stream);
}

// Round 5
// 98.795 us; speedup vs baseline: 1.0706x; 1.0706x over previous
//
#include <hip/hip_runtime.h>
#include <math.h>
#include <stdint.h>

#define N 2048
#define D 128
#define JS 16            // j-slices (and i-tiles): 16 x 16 blocks
#define BM 128           // i-rows per block
#define BN 128           // j-cols per block
#define NB 256           // blocks = JS*JS = one per CU
#define NT 512           // 8 waves

typedef __attribute__((ext_vector_type(8))) short bf16x8;
typedef __attribute__((ext_vector_type(4))) float f32x4;

// round-to-nearest-even fp32 -> bf16; also returns the bf16 value as fp32
__device__ __forceinline__ ushort f2bf(float x, float* back) {
    uint32_t u = __float_as_uint(x);
    uint32_t r = u + 0x7FFFu + ((u >> 16) & 1u);
    ushort hv = (ushort)(r >> 16);
    *back = __uint_as_float(((uint32_t)hv) << 16);
    return hv;
}

__global__ __launch_bounds__(NT) void fused_kernel(
    const float* __restrict__ q, const int* __restrict__ tgt,
    float* __restrict__ wpv, int* __restrict__ wpi,
    float* __restrict__ wnv, int* __restrict__ wni,
    float* __restrict__ tp, unsigned* __restrict__ cnt,
    unsigned* __restrict__ cnt2, float* __restrict__ out) {
    __shared__ ushort HJ[BN * D];  // 32 KB, XOR-swizzled rows (256 B/row)
    __shared__ ushort LJ[BN * D];  // 32 KB
    __shared__ float sni[BM];
    __shared__ float snj[BN];
    __shared__ int stj[BN];
    __shared__ float sred[8];
    __shared__ int sgo1, sgo2;

    const int b = blockIdx.x, ib = b >> 4, s = b & 15;
    const int i0 = ib * BM, j0 = s * BN;
    const int tid = threadIdx.x, w = tid >> 6, lane = tid & 63;
    const int lr = lane & 15, h = lane >> 4;
    const float4* q4 = reinterpret_cast<const float4*>(q);

    // ---- stage j-slice: fp32 -> (H,L) bf16 split into swizzled LDS + exact j-norms
    for (int c = tid; c < BN * 16; c += NT) {
        const int row = c >> 4, col = c & 15;
        float4 v0 = q4[(j0 + row) * 32 + col * 2];
        float4 v1 = q4[(j0 + row) * 32 + col * 2 + 1];
        float xs[8] = {v0.x, v0.y, v0.z, v0.w, v1.x, v1.y, v1.z, v1.w};
        uint hp[4], lp[4];
        float ss = 0.f;
#pragma unroll
        for (int e = 0; e < 4; ++e) {
            float hb0, hb1, d0, d1;
            ushort h0 = f2bf(xs[2 * e], &hb0);
            ushort h1 = f2bf(xs[2 * e + 1], &hb1);
            ushort l0 = f2bf(xs[2 * e] - hb0, &d0);
            ushort l1 = f2bf(xs[2 * e + 1] - hb1, &d1);
            hp[e] = (uint)h0 | ((uint)h1 << 16);
            lp[e] = (uint)l0 | ((uint)l1 << 16);
            ss = fmaf(xs[2 * e], xs[2 * e], ss);
            ss = fmaf(xs[2 * e + 1], xs[2 * e + 1], ss);
        }
        const int boff = row * 256 + ((col * 16) ^ ((row & 7) << 4));
        *reinterpret_cast<uint4*>((char*)HJ + boff) = make_uint4(hp[0], hp[1], hp[2], hp[3]);
        *reinterpret_cast<uint4*>((char*)LJ + boff) = make_uint4(lp[0], lp[1], lp[2], lp[3]);
        // the 16 granules of this row live in 16 consecutive lanes: butterfly-sum
        ss += __shfl_xor(ss, 1); ss += __shfl_xor(ss, 2);
        ss += __shfl_xor(ss, 4); ss += __shfl_xor(ss, 8);
        if ((tid & 15) == 0) snj[row] = ss;
    }
    if (tid < BN) stj[tid] = tgt[j0 + tid];

    // ---- A fragments in registers + exact i-norms (lane (lr,h) owns row rowbase+lr)
    const int rowbase = i0 + w * 16;
    bf16x8 AH[4], AL[4];
    float na = 0.f;
#pragma unroll
    for (int kk = 0; kk < 4; ++kk) {
        float4 u0 = q4[(rowbase + lr) * 32 + kk * 8 + h * 2];
        float4 u1 = q4[(rowbase + lr) * 32 + kk * 8 + h * 2 + 1];
        float xs[8] = {u0.x, u0.y, u0.z, u0.w, u1.x, u1.y, u1.z, u1.w};
#pragma unroll
        for (int e = 0; e < 8; ++e) {
            float hb, d_;
            ushort hv = f2bf(xs[e], &hb);
            ushort lv = f2bf(xs[e] - hb, &d_);
            AH[kk][e] = (short)hv;
            AL[kk][e] = (short)lv;
            na = fmaf(xs[e], xs[e], na);
        }
    }
    na += __shfl_xor(na, 16);  // lanes sharing lr hold disjoint col-slices
    na += __shfl_xor(na, 32);
    if (h == 0) sni[w * 16 + lr] = na;
    __syncthreads();

    float ni[4]; int ti[4];
#pragma unroll
    for (int m = 0; m < 4; ++m) {
        ni[m] = sni[w * 16 + h * 4 + m];
        ti[m] = tgt[rowbase + h * 4 + m];
    }
    float njr[8]; int tjr[8];
#pragma unroll
    for (int ct = 0; ct < 8; ++ct) {
        njr[ct] = snj[ct * 16 + lr];
        tjr[ct] = stj[ct * 16 + lr];
    }

    float bpv[4], bnv[4];
    int bpi[4], bni[4];
#pragma unroll
    for (int m = 0; m < 4; ++m) {
        bpv[m] = -INFINITY; bpi[m] = 0;
        bnv[m] = INFINITY;  bni[m] = 0;
    }

    // ---- MFMA pair scan over 8 column-tiles of 16 ----
    for (int ct = 0; ct < BN / 16; ++ct) {
        const int brow = ct * 16 + lr;
        const int bswz = (brow & 7) << 4;
        const char* hbase = (const char*)HJ + brow * 256;
        const char* lbase = (const char*)LJ + brow * 256;
        bf16x8 BH[4], BL[4];
#pragma unroll
        for (int kk = 0; kk < 4; ++kk) {
            int off = (kk * 64 + h * 16) ^ bswz;
            BH[kk] = *reinterpret_cast<const bf16x8*>(hbase + off);
            BL[kk] = *reinterpret_cast<const bf16x8*>(lbase + off);
        }
        // 4 independent accumulator chains (HH, HL, LH, LL) for ILP
        f32x4 a0 = (f32x4){0.f, 0.f, 0.f, 0.f};
        f32x4 a1 = (f32x4){0.f, 0.f, 0.f, 0.f};
        f32x4 a2 = (f32x4){0.f, 0.f, 0.f, 0.f};
        f32x4 a3 = (f32x4){0.f, 0.f, 0.f, 0.f};
#pragma unroll
        for (int kk = 0; kk < 4; ++kk) {
            a0 = __builtin_amdgcn_mfma_f32_16x16x32_bf16(AH[kk], BH[kk], a0, 0, 0, 0);
            a1 = __builtin_amdgcn_mfma_f32_16x16x32_bf16(AH[kk], BL[kk], a1, 0, 0, 0);
            a2 = __builtin_amdgcn_mfma_f32_16x16x32_bf16(AL[kk], BH[kk], a2, 0, 0, 0);
            a3 = __builtin_amdgcn_mfma_f32_16x16x32_bf16(AL[kk], BL[kk], a3, 0, 0, 0);
        }
        f32x4 acc = (a0 + a1) + (a2 + a3);

        const int jg = j0 + ct * 16 + lr;
#pragma unroll
        for (int m = 0; m < 4; ++m) {
            const int ig = rowbase + h * 4 + m;
            const float dist = fmaf(-2.f, acc[m], ni[m] + njr[ct]);
            const bool same = (ti[m] == tjr[ct]);
            const bool diag = (ig == jg);
            const float pmv = diag ? -INFINITY : (same ? dist : 0.f);
            if (pmv > bpv[m]) { bpv[m] = pmv; bpi[m] = jg; }
            const float nmv = (same || diag) ? INFINITY : dist;
            if (nmv < bnv[m]) { bnv[m] = nmv; bni[m] = jg; }
        }
    }

    // ---- merge across the 16 lanes sharing each C row (index tie-break) ----
#pragma unroll
    for (int mask = 1; mask <= 8; mask <<= 1) {
#pragma unroll
        for (int m = 0; m < 4; ++m) {
            float ov = __shfl_xor(bpv[m], mask);
            int oi = __shfl_xor(bpi[m], mask);
            if (ov > bpv[m] || (ov == bpv[m] && oi < bpi[m])) {
                bpv[m] = ov; bpi[m] = oi;
            }
            float onv = __shfl_xor(bnv[m], mask);
            int oni = __shfl_xor(bni[m], mask);
            if (onv < bnv[m] || (onv == bnv[m] && oni < bni[m])) {
                bnv[m] = onv; bni[m] = oni;
            }
        }
    }
    if (lr == 0) {
#pragma unroll
        for (int m = 0; m < 4; ++m) {
            int r = rowbase + h * 4 + m;
            int idx = r * JS + s;
            wpv[idx] = bpv[m]; wpi[idx] = bpi[m];
            wnv[idx] = bnv[m]; wni[idx] = bni[m];
        }
    }

    // ---- ticket 1: last block of this i-tile finalizes its 128 rows ----
    __threadfence();
    if (tid == 0) sgo1 = ((atomicAdd(&cnt[ib], 1u) & 15u) == 15u) ? 1 : 0;
    __syncthreads();
    if (sgo1) {
        __threadfence();  // acquire: other blocks' slice results
        const float2* q2 = reinterpret_cast<const float2*>(q);
        float wsum = 0.f;
        for (int rr = 0; rr < 16; ++rr) {
            const int i = i0 + w * 16 + rr;
            const int l = lane & 15;
            float pv = wpv[i * JS + l];
            int pi = wpi[i * JS + l];
            float nv = wnv[i * JS + l];
            int ng = wni[i * JS + l];
#pragma unroll
            for (int mask = 1; mask <= 8; mask <<= 1) {
                float opv = __shfl_xor(pv, mask);
                int opi = __shfl_xor(pi, mask);
                if (opv > pv || (opv == pv && opi < pi)) { pv = opv; pi = opi; }
                float onv = __shfl_xor(nv, mask);
                int oni = __shfl_xor(ng, mask);
                if (onv < nv || (onv == nv && oni < ng)) { nv = onv; ng = oni; }
            }
            // exact fp32 recompute, coalesced: 64 lanes x float2 = one 512B row
            float2 a = q2[i * (D / 2) + lane];
            float2 p = q2[pi * (D / 2) + lane];
            float2 g = q2[ng * (D / 2) + lane];
            float dp = (a.x - p.x) * (a.x - p.x) + (a.y - p.y) * (a.y - p.y);
            float dn = (a.x - g.x) * (a.x - g.x) + (a.y - g.y) * (a.y - g.y);
#pragma unroll
            for (int mask = 1; mask <= 32; mask <<= 1) {
                dp += __shfl_xor(dp, mask);
                dn += __shfl_xor(dn, mask);
            }
            if (lane == 0) wsum += fmaxf(0.f, 1.0f - dp + dn);
        }
        if (lane == 0) sred[w] = wsum;
        __syncthreads();
        if (tid == 0) {
            float t = 0.f;
#pragma unroll
            for (int k = 0; k < 8; ++k) t += sred[k];
            tp[ib] = t;
            __threadfence();
            sgo2 = ((atomicAdd(cnt2, 1u) & 15u) == 15u) ? 1 : 0;
        }
        __syncthreads();
        // ---- ticket 2: last tile-finalizer sums the 16 tile partials ----
        if (sgo2 && w == 0) {
            __threadfence();
            float v = (lane < 16) ? tp[lane] : 0.f;
#pragma unroll
            for (int mask = 1; mask <= 8; mask <<= 1) v += __shfl_xor(v, mask);
            if (lane == 0) out[0] = v / (float)N;
        }
    }
}

extern "C" void kernel_launch(void* const* d_in, const int* in_sizes, int n_in,
                              void* d_out, int out_size, void* d_ws, size_t ws_size,
                              hipStream_t stream) {
    const float* q = (const float*)d_in[0];
    const int* tgt = (const int*)d_in[1];

    unsigned* cnt = (unsigned*)d_ws;                    // 16 (mod-16 tickets: no reset needed)
    unsigned* cnt2 = cnt + 16;                          // 1
    float* wpv = (float*)((char*)d_ws + 256);           // N*JS
    int* wpi = (int*)(wpv + N * JS);                    // N*JS
    float* wnv = (float*)(wpi + N * JS);                // N*JS
    int* wni = (int*)(wnv + N * JS);                    // N*JS
    float* tp = (float*)(wni + N * JS);                 // 16
    float* out = (float*)d_out;

    hipLaunchKernelGGL(fused_kernel, dim3(NB), dim3(NT), 0, stream,
                       q, tgt, wpv, wpi, wnv, wni, tp, cnt, cnt2, out);
}

// Round 6
// 28.615 us; speedup vs baseline: 3.6963x; 3.4525x over previous
//
#include <hip/hip_runtime.h>
#include <math.h>
#include <stdint.h>

#define N 2048
#define D 128
#define JS 16            // j-slices (and i-tiles): 16 x 16 blocks
#define BM 128           // i-rows per block
#define BN 128           // j-cols per block
#define NB 256           // blocks = JS*JS = one per CU
#define NT 512           // 8 waves

typedef __attribute__((ext_vector_type(8))) short bf16x8;
typedef __attribute__((ext_vector_type(4))) float f32x4;

// round-to-nearest-even fp32 -> bf16; also returns the bf16 value as fp32
__device__ __forceinline__ ushort f2bf(float x, float* back) {
    uint32_t u = __float_as_uint(x);
    uint32_t r = u + 0x7FFFu + ((u >> 16) & 1u);
    ushort hv = (ushort)(r >> 16);
    *back = __uint_as_float(((uint32_t)hv) << 16);
    return hv;
}

__global__ __launch_bounds__(NT) void pair_kernel(
    const float* __restrict__ q, const int* __restrict__ tgt,
    float* __restrict__ wpv, int* __restrict__ wpi,
    float* __restrict__ wnv, int* __restrict__ wni,
    unsigned long long* __restrict__ sum_acc) {
    __shared__ ushort HJ[BN * D];  // 32 KB, XOR-swizzled rows (256 B/row)
    __shared__ ushort LJ[BN * D];  // 32 KB
    __shared__ float sni[BM];
    __shared__ float snj[BN];
    __shared__ int stj[BN];

    const int b = blockIdx.x, ib = b >> 4, s = b & 15;
    const int i0 = ib * BM, j0 = s * BN;
    const int tid = threadIdx.x, w = tid >> 6, lane = tid & 63;
    const int lr = lane & 15, h = lane >> 4;
    const float4* q4 = reinterpret_cast<const float4*>(q);

    // reset the fixed-point loss accumulator for this call (K1->K2 kernel
    // boundary makes this visible to K2's atomics; no fence needed here)
    if (b == 0 && tid == 0) *sum_acc = 0ULL;

    // ---- stage j-slice: fp32 -> (H,L) bf16 split into swizzled LDS + exact j-norms
    for (int c = tid; c < BN * 16; c += NT) {
        const int row = c >> 4, col = c & 15;
        float4 v0 = q4[(j0 + row) * 32 + col * 2];
        float4 v1 = q4[(j0 + row) * 32 + col * 2 + 1];
        float xs[8] = {v0.x, v0.y, v0.z, v0.w, v1.x, v1.y, v1.z, v1.w};
        uint hp[4], lp[4];
        float ss = 0.f;
#pragma unroll
        for (int e = 0; e < 4; ++e) {
            float hb0, hb1, d0, d1;
            ushort h0 = f2bf(xs[2 * e], &hb0);
            ushort h1 = f2bf(xs[2 * e + 1], &hb1);
            ushort l0 = f2bf(xs[2 * e] - hb0, &d0);
            ushort l1 = f2bf(xs[2 * e + 1] - hb1, &d1);
            hp[e] = (uint)h0 | ((uint)h1 << 16);
            lp[e] = (uint)l0 | ((uint)l1 << 16);
            ss = fmaf(xs[2 * e], xs[2 * e], ss);
            ss = fmaf(xs[2 * e + 1], xs[2 * e + 1], ss);
        }
        const int boff = row * 256 + ((col * 16) ^ ((row & 7) << 4));
        *reinterpret_cast<uint4*>((char*)HJ + boff) = make_uint4(hp[0], hp[1], hp[2], hp[3]);
        *reinterpret_cast<uint4*>((char*)LJ + boff) = make_uint4(lp[0], lp[1], lp[2], lp[3]);
        // the 16 granules of this row live in 16 consecutive lanes: butterfly-sum
        ss += __shfl_xor(ss, 1); ss += __shfl_xor(ss, 2);
        ss += __shfl_xor(ss, 4); ss += __shfl_xor(ss, 8);
        if ((tid & 15) == 0) snj[row] = ss;
    }
    if (tid < BN) stj[tid] = tgt[j0 + tid];

    // ---- A fragments in registers + exact i-norms (lane (lr,h) owns row rowbase+lr)
    const int rowbase = i0 + w * 16;
    bf16x8 AH[4], AL[4];
    float na = 0.f;
#pragma unroll
    for (int kk = 0; kk < 4; ++kk) {
        float4 u0 = q4[(rowbase + lr) * 32 + kk * 8 + h * 2];
        float4 u1 = q4[(rowbase + lr) * 32 + kk * 8 + h * 2 + 1];
        float xs[8] = {u0.x, u0.y, u0.z, u0.w, u1.x, u1.y, u1.z, u1.w};
#pragma unroll
        for (int e = 0; e < 8; ++e) {
            float hb, d_;
            ushort hv = f2bf(xs[e], &hb);
            ushort lv = f2bf(xs[e] - hb, &d_);
            AH[kk][e] = (short)hv;
            AL[kk][e] = (short)lv;
            na = fmaf(xs[e], xs[e], na);
        }
    }
    na += __shfl_xor(na, 16);  // lanes sharing lr hold disjoint col-slices
    na += __shfl_xor(na, 32);
    if (h == 0) sni[w * 16 + lr] = na;
    __syncthreads();

    float ni[4]; int ti[4];
#pragma unroll
    for (int m = 0; m < 4; ++m) {
        ni[m] = sni[w * 16 + h * 4 + m];
        ti[m] = tgt[rowbase + h * 4 + m];
    }
    float njr[8]; int tjr[8];
#pragma unroll
    for (int ct = 0; ct < 8; ++ct) {
        njr[ct] = snj[ct * 16 + lr];
        tjr[ct] = stj[ct * 16 + lr];
    }

    float bpv[4], bnv[4];
    int bpi[4], bni[4];
#pragma unroll
    for (int m = 0; m < 4; ++m) {
        bpv[m] = -INFINITY; bpi[m] = 0;
        bnv[m] = INFINITY;  bni[m] = 0;
    }

    // ---- MFMA pair scan over 8 column-tiles of 16 ----
    for (int ct = 0; ct < BN / 16; ++ct) {
        const int brow = ct * 16 + lr;
        const int bswz = (brow & 7) << 4;
        const char* hbase = (const char*)HJ + brow * 256;
        const char* lbase = (const char*)LJ + brow * 256;
        bf16x8 BH[4], BL[4];
#pragma unroll
        for (int kk = 0; kk < 4; ++kk) {
            int off = (kk * 64 + h * 16) ^ bswz;
            BH[kk] = *reinterpret_cast<const bf16x8*>(hbase + off);
            BL[kk] = *reinterpret_cast<const bf16x8*>(lbase + off);
        }
        // 4 independent accumulator chains (HH, HL, LH, LL) for ILP
        f32x4 a0 = (f32x4){0.f, 0.f, 0.f, 0.f};
        f32x4 a1 = (f32x4){0.f, 0.f, 0.f, 0.f};
        f32x4 a2 = (f32x4){0.f, 0.f, 0.f, 0.f};
        f32x4 a3 = (f32x4){0.f, 0.f, 0.f, 0.f};
#pragma unroll
        for (int kk = 0; kk < 4; ++kk) {
            a0 = __builtin_amdgcn_mfma_f32_16x16x32_bf16(AH[kk], BH[kk], a0, 0, 0, 0);
            a1 = __builtin_amdgcn_mfma_f32_16x16x32_bf16(AH[kk], BL[kk], a1, 0, 0, 0);
            a2 = __builtin_amdgcn_mfma_f32_16x16x32_bf16(AL[kk], BH[kk], a2, 0, 0, 0);
            a3 = __builtin_amdgcn_mfma_f32_16x16x32_bf16(AL[kk], BL[kk], a3, 0, 0, 0);
        }
        f32x4 acc = (a0 + a1) + (a2 + a3);

        const int jg = j0 + ct * 16 + lr;
#pragma unroll
        for (int m = 0; m < 4; ++m) {
            const int ig = rowbase + h * 4 + m;
            const float dist = fmaf(-2.f, acc[m], ni[m] + njr[ct]);
            const bool same = (ti[m] == tjr[ct]);
            const bool diag = (ig == jg);
            const float pmv = diag ? -INFINITY : (same ? dist : 0.f);
            if (pmv > bpv[m]) { bpv[m] = pmv; bpi[m] = jg; }
            const float nmv = (same || diag) ? INFINITY : dist;
            if (nmv < bnv[m]) { bnv[m] = nmv; bni[m] = jg; }
        }
    }

    // ---- merge across the 16 lanes sharing each C row (index tie-break) ----
#pragma unroll
    for (int mask = 1; mask <= 8; mask <<= 1) {
#pragma unroll
        for (int m = 0; m < 4; ++m) {
            float ov = __shfl_xor(bpv[m], mask);
            int oi = __shfl_xor(bpi[m], mask);
            if (ov > bpv[m] || (ov == bpv[m] && oi < bpi[m])) {
                bpv[m] = ov; bpi[m] = oi;
            }
            float onv = __shfl_xor(bnv[m], mask);
            int oni = __shfl_xor(bni[m], mask);
            if (onv < bnv[m] || (onv == bnv[m] && oni < bni[m])) {
                bnv[m] = onv; bni[m] = oni;
            }
        }
    }
    if (lr == 0) {
#pragma unroll
        for (int m = 0; m < 4; ++m) {
            int r = rowbase + h * 4 + m;
            int idx = r * JS + s;
            wpv[idx] = bpv[m]; wpi[idx] = bpi[m];
            wnv[idx] = bnv[m]; wni[idx] = bni[m];
        }
    }
}

// 64 blocks x 4 waves; wave handles 8 rows: slice merge + exact fp32 recompute.
// Mean via deterministic 2^32 fixed-point u64 atomics + mod-64 ticket (works
// from any initial ticket value; sum_acc zeroed by pair_kernel each call).
__global__ __launch_bounds__(256) void finalize_kernel(
    const float* __restrict__ q, const float* __restrict__ wpv, const int* __restrict__ wpi,
    const float* __restrict__ wnv, const int* __restrict__ wni,
    unsigned long long* __restrict__ sum_acc, unsigned* __restrict__ ticket,
    float* __restrict__ out) {
    __shared__ float red[4];
    const int wave = threadIdx.x >> 6;
    const int lane = threadIdx.x & 63;
    const int l = lane & 15;
    const float2* q2 = reinterpret_cast<const float2*>(q);
    float lsum = 0.f;
#pragma unroll
    for (int r = 0; r < 8; ++r) {
        const int i = blockIdx.x * 32 + wave * 8 + r;
        // lane-parallel slice merge (all four 16-lane groups duplicate -> identical)
        float pv = wpv[i * JS + l];
        int pi = wpi[i * JS + l];
        float nv = wnv[i * JS + l];
        int ng = wni[i * JS + l];
#pragma unroll
        for (int mask = 1; mask <= 8; mask <<= 1) {
            float opv = __shfl_xor(pv, mask);
            int opi = __shfl_xor(pi, mask);
            if (opv > pv || (opv == pv && opi < pi)) { pv = opv; pi = opi; }
            float onv = __shfl_xor(nv, mask);
            int oni = __shfl_xor(ng, mask);
            if (onv < nv || (onv == nv && oni < ng)) { nv = onv; ng = oni; }
        }
        // exact fp32 recompute, coalesced: 64 lanes x float2 = one 512B row
        float2 a = q2[i * (D / 2) + lane];
        float2 p = q2[pi * (D / 2) + lane];
        float2 g = q2[ng * (D / 2) + lane];
        float dp = (a.x - p.x) * (a.x - p.x) + (a.y - p.y) * (a.y - p.y);
        float dn = (a.x - g.x) * (a.x - g.x) + (a.y - g.y) * (a.y - g.y);
#pragma unroll
        for (int mask = 1; mask <= 32; mask <<= 1) {
            dp += __shfl_xor(dp, mask);
            dn += __shfl_xor(dn, mask);
        }
        if (lane == 0) lsum += fmaxf(0.f, 1.0f - dp + dn);
    }
    if (lane == 0) red[wave] = lsum;
    __syncthreads();
    if (threadIdx.x == 0) {
        float bsum = red[0] + red[1] + red[2] + red[3];
        unsigned long long fix = (unsigned long long)((double)bsum * 4294967296.0);
        unsigned long long old = atomicAdd(sum_acc, fix);
        // consume 'old' (forces vmcnt wait -> sum-add performed) and pin the
        // ticket add behind it ("memory" clobber stops reordering)
        asm volatile("" : : "v"((unsigned)old) : "memory");
        unsigned t = atomicAdd(ticket, 1u);
        if ((t & 63u) == 63u) {  // last of 64 blocks: all sum-adds are in
            unsigned long long tot = atomicAdd(sum_acc, 0ULL);
            out[0] = (float)((double)tot / 4294967296.0 / (double)N);
        }
    }
}

extern "C" void kernel_launch(void* const* d_in, const int* in_sizes, int n_in,
                              void* d_out, int out_size, void* d_ws, size_t ws_size,
                              hipStream_t stream) {
    const float* q = (const float*)d_in[0];
    const int* tgt = (const int*)d_in[1];

    unsigned long long* sum_acc = (unsigned long long*)d_ws;  // 8 B, zeroed by K1
    unsigned* ticket = (unsigned*)((char*)d_ws + 8);          // mod-64: no reset needed
    float* wpv = (float*)((char*)d_ws + 256);                 // N*JS
    int* wpi = (int*)(wpv + N * JS);                          // N*JS
    float* wnv = (float*)(wpi + N * JS);                      // N*JS
    int* wni = (int*)(wnv + N * JS);                          // N*JS
    float* out = (float*)d_out;

    hipLaunchKernelGGL(pair_kernel, dim3(NB), dim3(NT), 0, stream,
                       q, tgt, wpv, wpi, wnv, wni, sum_acc);
    hipLaunchKernelGGL(finalize_kernel, dim3(64), dim3(256), 0, stream,
                       q, wpv, wpi, wnv, wni, sum_acc, ticket, out);
}